// Round 1
// baseline (1787.539 us; speedup 1.0000x reference)
//
#include <hip/hip_runtime.h>

#define Bz 8
#define T1z 13
#define Tz 12
#define Vz 20000
#define Ez 512
#define Dz 512
#define Kz 512
#define Cz 2048
#define Pz 64

__device__ __forceinline__ float waveReduce(float v) {
    #pragma unroll
    for (int off = 32; off > 0; off >>= 1) v += __shfl_down(v, off);
    return v;
}

__device__ __forceinline__ float sigf(float x) {
    return 1.0f / (1.0f + expf(-x));
}

// ---- fill outputs 2..5 (captions, decode_lengths, alphas=0, sort_ind) ----
__global__ void k_tail(const int* __restrict__ caps, const int* __restrict__ caplen,
                       float* __restrict__ out) {
    int idx = blockIdx.x * 256 + threadIdx.x;
    const int base = Bz * Tz * Vz;               // 1920000
    const int nCap = Bz * T1z;                   // 104
    const int nLen = Bz;                         // 8
    const int nAlp = Bz * Tz * Pz;               // 6144
    if (idx < nCap) {
        out[base + idx] = (float)caps[idx];
    } else if (idx < nCap + nLen) {
        out[base + idx] = (float)(caplen[idx - nCap] - 1);
    } else if (idx < nCap + nLen + nAlp) {
        out[base + idx] = 0.0f;
    } else if (idx < nCap + nLen + nAlp + Bz) {
        out[base + idx] = (float)(idx - (nCap + nLen + nAlp));
    }
}

// ---- Vmean[b,c] = mean over P of enc ----
__global__ void k_vmean(const float* __restrict__ enc, float* __restrict__ vmean) {
    int gid = blockIdx.x * 256 + threadIdx.x;
    int w = gid >> 6, lane = gid & 63;           // w in [0, B*C)
    float v = enc[w * 64 + lane];
    v = waveReduce(v);
    if (lane == 0) vmean[w] = v * (1.0f / 64.0f);
}

// ---- h0, c0 = Vmean @ W_init.T + b ----
__global__ void k_init_hc(const float* __restrict__ vmean,
                          const float* __restrict__ Wh, const float* __restrict__ bh,
                          const float* __restrict__ Wc, const float* __restrict__ bc,
                          float* __restrict__ h, float* __restrict__ c) {
    int gid = blockIdx.x * 256 + threadIdx.x;
    int w = gid >> 6, lane = gid & 63;           // w in [0, 2*B*D)
    int which = w / (Bz * Dz);
    int rem = w % (Bz * Dz);
    int b = rem / Dz, d = rem % Dz;
    const float* W = which ? Wc : Wh;
    float acc = 0.0f;
    #pragma unroll
    for (int i = 0; i < Cz / 64; i++) {
        int cc = i * 64 + lane;
        acc += vmean[b * Cz + cc] * W[d * Cz + cc];
    }
    acc = waveReduce(acc);
    if (lane == 0) {
        if (which) c[rem] = acc + bc[d];
        else       h[rem] = acc + bh[d];
    }
}

// ---- qc[b,k] = b_c[k] + h @ W_hc ; qs[b,k] = b_s[k] + h @ W_hs ----
__global__ void k_qcqs(const float* __restrict__ h,
                       const float* __restrict__ W_hc, const float* __restrict__ b_c,
                       const float* __restrict__ W_hs, const float* __restrict__ b_s,
                       float* __restrict__ qc, float* __restrict__ qs) {
    int gid = blockIdx.x * 256 + threadIdx.x;    // [0, 2*B*K)
    int which = gid / (Bz * Kz);
    int rem = gid % (Bz * Kz);
    int b = rem / Kz, k = rem % Kz;
    const float* W = which ? W_hs : W_hc;
    float acc = which ? b_s[k] : b_c[k];
    for (int d = 0; d < Dz; d++) acc += h[b * Dz + d] * W[d * Kz + k];
    if (which) qs[rem] = acc; else qc[rem] = acc;
}

// ---- channel attention scores: sc[b,c] = b_i_hat + sum_k tanh(v*W_c[k]+qc[b,k])*W_i_hat[k]
__global__ void k_attc(const float* __restrict__ vmean, const float* __restrict__ W_c,
                       const float* __restrict__ qc, const float* __restrict__ W_i_hat,
                       const float* __restrict__ b_i_hat, float* __restrict__ sc) {
    int gid = blockIdx.x * 256 + threadIdx.x;
    int w = gid >> 6, lane = gid & 63;           // w in [0, B*C)
    int b = w / Cz;
    float v = vmean[w];
    float acc = 0.0f;
    #pragma unroll
    for (int i = 0; i < Kz / 64; i++) {
        int k = i * 64 + lane;
        acc += tanhf(fmaf(v, W_c[k], qc[b * Kz + k])) * W_i_hat[k];
    }
    acc = waveReduce(acc);
    if (lane == 0) sc[w] = acc + b_i_hat[0];
}

// ---- beta = softmax over batch axis, per channel ----
__global__ void k_beta(const float* __restrict__ sc, float* __restrict__ beta) {
    int c = blockIdx.x * 256 + threadIdx.x;
    if (c >= Cz) return;
    float m = -1e30f;
    for (int b = 0; b < Bz; b++) m = fmaxf(m, sc[b * Cz + c]);
    float e[Bz]; float s = 0.0f;
    for (int b = 0; b < Bz; b++) { e[b] = expf(sc[b * Cz + c] - m); s += e[b]; }
    float inv = 1.0f / s;
    for (int b = 0; b < Bz; b++) beta[b * Cz + c] = e[b] * inv;
}

// ---- partial einsum: part[cs][b][p][k] = sum_{c in slice} enc[b,c,p]*beta[b,c]*W_s[c,k]
__global__ __launch_bounds__(256) void k_atts_gemm(const float* __restrict__ enc,
                                                   const float* __restrict__ beta,
                                                   const float* __restrict__ W_s,
                                                   float* __restrict__ part) {
    __shared__ __align__(16) float As[64][64];
    __shared__ __align__(16) float Bs[64][64];
    int bid = blockIdx.x;
    int cslice = bid & 3, ktile = (bid >> 2) & 7, b = bid >> 5;
    int tid = threadIdx.x;
    int kq = tid & 15, pq = tid >> 4;
    float acc[4][4] = {};
    for (int chunk = 0; chunk < 8; chunk++) {
        int c0 = cslice * 512 + chunk * 64;
        #pragma unroll
        for (int i = 0; i < 16; i++) {
            int idx = tid + i * 256;
            int cl = idx >> 6, p = idx & 63;
            As[cl][p] = enc[(b * Cz + c0 + cl) * 64 + p] * beta[b * Cz + c0 + cl];
            Bs[cl][p] = W_s[(c0 + cl) * Kz + ktile * 64 + p];
        }
        __syncthreads();
        #pragma unroll 4
        for (int cc = 0; cc < 64; cc++) {
            const float4 av = *(const float4*)&As[cc][pq << 2];
            const float4 bv = *(const float4*)&Bs[cc][kq << 2];
            acc[0][0] = fmaf(av.x, bv.x, acc[0][0]);
            acc[0][1] = fmaf(av.x, bv.y, acc[0][1]);
            acc[0][2] = fmaf(av.x, bv.z, acc[0][2]);
            acc[0][3] = fmaf(av.x, bv.w, acc[0][3]);
            acc[1][0] = fmaf(av.y, bv.x, acc[1][0]);
            acc[1][1] = fmaf(av.y, bv.y, acc[1][1]);
            acc[1][2] = fmaf(av.y, bv.z, acc[1][2]);
            acc[1][3] = fmaf(av.y, bv.w, acc[1][3]);
            acc[2][0] = fmaf(av.z, bv.x, acc[2][0]);
            acc[2][1] = fmaf(av.z, bv.y, acc[2][1]);
            acc[2][2] = fmaf(av.z, bv.z, acc[2][2]);
            acc[2][3] = fmaf(av.z, bv.w, acc[2][3]);
            acc[3][0] = fmaf(av.w, bv.x, acc[3][0]);
            acc[3][1] = fmaf(av.w, bv.y, acc[3][1]);
            acc[3][2] = fmaf(av.w, bv.z, acc[3][2]);
            acc[3][3] = fmaf(av.w, bv.w, acc[3][3]);
        }
        __syncthreads();
    }
    float* dst = part + (size_t)((cslice * Bz + b) * Pz) * Kz + ktile * 64 + (kq << 2);
    #pragma unroll
    for (int i = 0; i < 4; i++) {
        int p = (pq << 2) + i;
        float4 w = make_float4(acc[i][0], acc[i][1], acc[i][2], acc[i][3]);
        *(float4*)&dst[(size_t)p * Kz] = w;
    }
}

// ---- spatial attention scores: s2[b,p] = b_i + sum_k tanh(sum_parts + qs[b,k]) * W_i[k]
__global__ void k_atts_score(const float* __restrict__ part, const float* __restrict__ qs,
                             const float* __restrict__ W_i, const float* __restrict__ b_i,
                             float* __restrict__ s2) {
    int gid = blockIdx.x * 256 + threadIdx.x;
    int w = gid >> 6, lane = gid & 63;           // w in [0, B*P)
    int b = w / Pz, p = w % Pz;
    const int stride = Bz * Pz * Kz;
    float acc = 0.0f;
    #pragma unroll
    for (int i = 0; i < Kz / 64; i++) {
        int k = i * 64 + lane;
        int base = (b * Pz + p) * Kz + k;
        float val = qs[b * Kz + k] + part[base] + part[stride + base]
                  + part[2 * stride + base] + part[3 * stride + base];
        acc += tanhf(val) * W_i[k];
    }
    acc = waveReduce(acc);
    if (lane == 0) s2[w] = acc + b_i[0];
}

// ---- alpha softmax (inline, per-block) + awe[b,c] = beta*mean_p(enc*alpha) ----
__global__ void k_awe(const float* __restrict__ enc, const float* __restrict__ beta,
                      const float* __restrict__ s2, float* __restrict__ awe) {
    __shared__ float alpha_s[Bz * Pz];
    int tid = threadIdx.x;
    if (tid < Pz) {
        float m = -1e30f;
        for (int b = 0; b < Bz; b++) m = fmaxf(m, s2[b * Pz + tid]);
        float e[Bz]; float s = 0.0f;
        for (int b = 0; b < Bz; b++) { e[b] = expf(s2[b * Pz + tid] - m); s += e[b]; }
        float inv = 1.0f / s;
        for (int b = 0; b < Bz; b++) alpha_s[b * Pz + tid] = e[b] * inv;
    }
    __syncthreads();
    int gid = blockIdx.x * 256 + tid;
    int w = gid >> 6, lane = gid & 63;           // w in [0, B*C)
    int b = w / Cz;
    float v = enc[w * 64 + lane] * alpha_s[b * Pz + lane];
    v = waveReduce(v);
    if (lane == 0) awe[w] = beta[w] * v * (1.0f / 64.0f);
}

// ---- gates[b,j] = b_ih[j]+b_hh[j] + x @ W_ih.T + h @ W_hh.T  (wave per j, 8 batches) ----
__global__ void k_gates(const float* __restrict__ emb, const int* __restrict__ caps,
                        const float* __restrict__ awe, const float* __restrict__ h,
                        const float* __restrict__ W_ih, const float* __restrict__ W_hh,
                        const float* __restrict__ b_ih, const float* __restrict__ b_hh,
                        float* __restrict__ gates, int t) {
    int gid = blockIdx.x * 256 + threadIdx.x;
    int j = gid >> 6, lane = gid & 63;           // j in [0, 4*D)
    int tok[Bz];
    #pragma unroll
    for (int b = 0; b < Bz; b++) tok[b] = caps[b * T1z + t];
    float acc[Bz] = {};
    for (int i = 0; i < 48; i++) {               // e = 0..3071
        int e = i * 64 + lane;
        float wv = (e < 2560) ? W_ih[(size_t)j * 2560 + e] : W_hh[(size_t)j * 512 + (e - 2560)];
        if (e < Ez) {
            #pragma unroll
            for (int b = 0; b < Bz; b++) acc[b] = fmaf(wv, emb[(size_t)tok[b] * Ez + e], acc[b]);
        } else if (e < 2560) {
            #pragma unroll
            for (int b = 0; b < Bz; b++) acc[b] = fmaf(wv, awe[b * Cz + (e - 512)], acc[b]);
        } else {
            #pragma unroll
            for (int b = 0; b < Bz; b++) acc[b] = fmaf(wv, h[b * Dz + (e - 2560)], acc[b]);
        }
    }
    float bias = b_ih[j] + b_hh[j];
    #pragma unroll
    for (int b = 0; b < Bz; b++) {
        float r = waveReduce(acc[b]);
        if (lane == 0) gates[b * (4 * Dz) + j] = r + bias;
    }
}

// ---- LSTM cell update (in place) ----
__global__ void k_cell(const float* __restrict__ gates, float* __restrict__ h, float* __restrict__ c) {
    int idx = blockIdx.x * 256 + threadIdx.x;    // [0, B*D)
    int b = idx / Dz, d = idx % Dz;
    const float* g = gates + b * (4 * Dz);
    float ig = sigf(g[d]);
    float fg = sigf(g[512 + d]);
    float gg = tanhf(g[1024 + d]);
    float og = sigf(g[1536 + d]);
    float cn = fg * c[idx] + ig * gg;
    c[idx] = cn;
    h[idx] = og * tanhf(cn);
}

// ---- preds[b,t,v] = h @ W_fc.T + b_fc  (wave per v, 8 batches) ----
__global__ void k_preds(const float* __restrict__ h, const float* __restrict__ W_fc,
                        const float* __restrict__ b_fc, float* __restrict__ out, int t) {
    int gid = blockIdx.x * 256 + threadIdx.x;
    int v = gid >> 6, lane = gid & 63;           // v in [0, V)
    float acc[Bz] = {};
    #pragma unroll
    for (int i = 0; i < Dz / 64; i++) {
        int d = i * 64 + lane;
        float wv = W_fc[(size_t)v * Dz + d];
        #pragma unroll
        for (int b = 0; b < Bz; b++) acc[b] = fmaf(wv, h[b * Dz + d], acc[b]);
    }
    float bias = b_fc[v];
    #pragma unroll
    for (int b = 0; b < Bz; b++) {
        float r = waveReduce(acc[b]);
        if (lane == 0) out[((size_t)b * Tz + t) * Vz + v] = r + bias;
    }
}

extern "C" void kernel_launch(void* const* d_in, const int* in_sizes, int n_in,
                              void* d_out, int out_size, void* d_ws, size_t ws_size,
                              hipStream_t stream) {
    const float* enc      = (const float*)d_in[0];
    const int*   caps     = (const int*)d_in[1];
    const int*   caplen   = (const int*)d_in[2];
    const float* W_c      = (const float*)d_in[3];
    const float* W_hc     = (const float*)d_in[4];
    const float* W_i_hat  = (const float*)d_in[5];
    const float* b_c      = (const float*)d_in[6];
    const float* b_i_hat  = (const float*)d_in[7];
    const float* W_s      = (const float*)d_in[8];
    const float* W_hs     = (const float*)d_in[9];
    const float* W_i      = (const float*)d_in[10];
    const float* b_s      = (const float*)d_in[11];
    const float* b_i      = (const float*)d_in[12];
    const float* emb      = (const float*)d_in[13];
    const float* W_ih     = (const float*)d_in[14];
    const float* W_hh     = (const float*)d_in[15];
    const float* b_ih     = (const float*)d_in[16];
    const float* b_hh     = (const float*)d_in[17];
    const float* W_init_h = (const float*)d_in[18];
    const float* b_init_h = (const float*)d_in[19];
    const float* W_init_c = (const float*)d_in[20];
    const float* b_init_c = (const float*)d_in[21];
    const float* W_fc     = (const float*)d_in[22];
    const float* b_fc     = (const float*)d_in[23];
    float* out = (float*)d_out;
    float* ws  = (float*)d_ws;

    float* vmean = ws;                 // 16384
    float* h     = vmean + 16384;      // 4096
    float* c     = h + 4096;           // 4096
    float* qc    = c + 4096;           // 4096
    float* qs    = qc + 4096;          // 4096
    float* sc    = qs + 4096;          // 16384
    float* beta  = sc + 16384;         // 16384
    float* s2    = beta + 16384;       // 512
    float* awe   = s2 + 512;           // 16384
    float* gates = awe + 16384;        // 16384
    float* part  = gates + 16384;      // 4*8*64*512 = 1048576

    k_tail<<<25, 256, 0, stream>>>(caps, caplen, out);
    k_vmean<<<(Bz * Cz * 64) / 256, 256, 0, stream>>>(enc, vmean);
    k_init_hc<<<(2 * Bz * Dz * 64) / 256, 256, 0, stream>>>(vmean, W_init_h, b_init_h,
                                                            W_init_c, b_init_c, h, c);
    for (int t = 0; t < Tz; t++) {
        k_qcqs<<<(2 * Bz * Kz) / 256, 256, 0, stream>>>(h, W_hc, b_c, W_hs, b_s, qc, qs);
        k_attc<<<(Bz * Cz * 64) / 256, 256, 0, stream>>>(vmean, W_c, qc, W_i_hat, b_i_hat, sc);
        k_beta<<<Cz / 256, 256, 0, stream>>>(sc, beta);
        k_atts_gemm<<<256, 256, 0, stream>>>(enc, beta, W_s, part);
        k_atts_score<<<(Bz * Pz * 64) / 256, 256, 0, stream>>>(part, qs, W_i, b_i, s2);
        k_awe<<<(Bz * Cz * 64) / 256, 256, 0, stream>>>(enc, beta, s2, awe);
        k_gates<<<(4 * Dz * 64) / 256, 256, 0, stream>>>(emb, caps, awe, h, W_ih, W_hh,
                                                         b_ih, b_hh, gates, t);
        k_cell<<<(Bz * Dz) / 256, 256, 0, stream>>>(gates, h, c);
        k_preds<<<(Vz * 64) / 256, 256, 0, stream>>>(h, W_fc, b_fc, out, t);
    }
}

// Round 2
// 1352.399 us; speedup vs baseline: 1.3218x; 1.3218x over previous
//
#include <hip/hip_runtime.h>

#define Bz 8
#define T1z 13
#define Tz 12
#define Vz 20000
#define Ez 512
#define Dz 512
#define Kz 512
#define Cz 2048
#define Pz 64

__device__ __forceinline__ float waveReduce(float v) {
    #pragma unroll
    for (int off = 32; off > 0; off >>= 1) v += __shfl_xor(v, off);
    return v;
}

__device__ __forceinline__ float sigf(float x) {
    return 1.0f / (1.0f + expf(-x));
}

// ---- fill outputs 2..5 (captions, decode_lengths, alphas=0, sort_ind) ----
__global__ void k_tail(const int* __restrict__ caps, const int* __restrict__ caplen,
                       float* __restrict__ out) {
    int idx = blockIdx.x * 256 + threadIdx.x;
    const int base = Bz * Tz * Vz;
    const int nCap = Bz * T1z;
    const int nLen = Bz;
    const int nAlp = Bz * Tz * Pz;
    if (idx < nCap) {
        out[base + idx] = (float)caps[idx];
    } else if (idx < nCap + nLen) {
        out[base + idx] = (float)(caplen[idx - nCap] - 1);
    } else if (idx < nCap + nLen + nAlp) {
        out[base + idx] = 0.0f;
    } else if (idx < nCap + nLen + nAlp + Bz) {
        out[base + idx] = (float)(idx - (nCap + nLen + nAlp));
    }
}

// ---- Vmean[b,c] = mean over P of enc ----
__global__ void k_vmean(const float* __restrict__ enc, float* __restrict__ vmean) {
    int gid = blockIdx.x * 256 + threadIdx.x;
    int w = gid >> 6, lane = gid & 63;
    float v = enc[w * 64 + lane];
    v = waveReduce(v);
    if (lane == 0) vmean[w] = v * (1.0f / 64.0f);
}

// ---- h0, c0 = Vmean @ W_init.T + b ----
__global__ void k_init_hc(const float* __restrict__ vmean,
                          const float* __restrict__ Wh, const float* __restrict__ bh,
                          const float* __restrict__ Wc, const float* __restrict__ bc,
                          float* __restrict__ h, float* __restrict__ c) {
    int gid = blockIdx.x * 256 + threadIdx.x;
    int w = gid >> 6, lane = gid & 63;
    int which = w / (Bz * Dz);
    int rem = w % (Bz * Dz);
    int b = rem / Dz, d = rem % Dz;
    const float* W = which ? Wc : Wh;
    float acc = 0.0f;
    #pragma unroll
    for (int i = 0; i < Cz / 64; i++) {
        int cc = i * 64 + lane;
        acc += vmean[b * Cz + cc] * W[d * Cz + cc];
    }
    acc = waveReduce(acc);
    if (lane == 0) {
        if (which) c[rem] = acc + bc[d];
        else       h[rem] = acc + bh[d];
    }
}

// ---- qpart[(chunk*2+which)*8+b][k] = sum over d-chunk of h[b,d]*W[d,k]  (d-split 4)
__global__ __launch_bounds__(256) void k_qcqs(const float* __restrict__ h,
                                              const float* __restrict__ W_hc,
                                              const float* __restrict__ W_hs,
                                              float* __restrict__ qpart) {
    int bid = blockIdx.x;                 // 128 blocks
    int half = bid & 1;
    int comb = bid >> 1;                  // 0..63
    int b = comb & 7;
    int which = (comb >> 3) & 1;
    int chunk = comb >> 4;                // 0..3
    int k = half * 256 + threadIdx.x;
    const float* W = which ? W_hs : W_hc;
    const float* hb = h + b * Dz;
    float acc = 0.0f;
    int d0 = chunk * 128;
    #pragma unroll 8
    for (int d = d0; d < d0 + 128; d++) acc = fmaf(hb[d], W[d * Kz + k], acc);
    qpart[((chunk * 2 + which) * Bz + b) * Kz + k] = acc;
}

// ---- channel attention + batch softmax fused: block per c, wave per b ----
__global__ __launch_bounds__(512) void k_attc_beta(const float* __restrict__ vmean,
                                                   const float* __restrict__ W_c,
                                                   const float* __restrict__ b_c,
                                                   const float* __restrict__ qpart,
                                                   const float* __restrict__ W_i_hat,
                                                   float* __restrict__ beta) {
    int c = blockIdx.x;
    int b = threadIdx.x >> 6, lane = threadIdx.x & 63;
    float v = vmean[b * Cz + c];
    const float4* wc4 = (const float4*)W_c;
    const float4* bc4 = (const float4*)b_c;
    const float4* wi4 = (const float4*)W_i_hat;
    const float4* qp4 = (const float4*)qpart;
    float acc = 0.0f;
    #pragma unroll
    for (int i = 0; i < 2; i++) {
        int kq = i * 64 + lane;
        float4 q = bc4[kq];
        #pragma unroll
        for (int ch = 0; ch < 4; ch++) {
            float4 p = qp4[((ch * 2 + 0) * Bz + b) * (Kz / 4) + kq];
            q.x += p.x; q.y += p.y; q.z += p.z; q.w += p.w;
        }
        float4 wc = wc4[kq], wi = wi4[kq];
        acc += tanhf(fmaf(v, wc.x, q.x)) * wi.x;
        acc += tanhf(fmaf(v, wc.y, q.y)) * wi.y;
        acc += tanhf(fmaf(v, wc.z, q.z)) * wi.z;
        acc += tanhf(fmaf(v, wc.w, q.w)) * wi.w;
    }
    acc = waveReduce(acc);
    __shared__ float sL[Bz];
    if (lane == 0) sL[b] = acc;
    __syncthreads();
    if (threadIdx.x < Bz) {
        float m = -1e30f;
        #pragma unroll
        for (int j = 0; j < Bz; j++) m = fmaxf(m, sL[j]);
        float s = 0.0f;
        #pragma unroll
        for (int j = 0; j < Bz; j++) s += expf(sL[j] - m);
        beta[threadIdx.x * Cz + c] = expf(sL[threadIdx.x] - m) / s;
    }
}

// ---- partial einsum: spart[cs][b][p][k] = sum_{c in slice} enc[b,c,p]*beta[b,c]*W_s[c,k]
__global__ __launch_bounds__(256) void k_atts_gemm(const float* __restrict__ enc,
                                                   const float* __restrict__ beta,
                                                   const float* __restrict__ W_s,
                                                   float* __restrict__ part) {
    __shared__ __align__(16) float As[64][64];
    __shared__ __align__(16) float Bs[64][64];
    int bid = blockIdx.x;
    int cslice = bid & 3, ktile = (bid >> 2) & 7, b = bid >> 5;
    int tid = threadIdx.x;
    int kq = tid & 15, pq = tid >> 4;
    float acc[4][4] = {};
    for (int chunk = 0; chunk < 8; chunk++) {
        int c0 = cslice * 512 + chunk * 64;
        #pragma unroll
        for (int i = 0; i < 16; i++) {
            int idx = tid + i * 256;
            int cl = idx >> 6, p = idx & 63;
            As[cl][p] = enc[(b * Cz + c0 + cl) * 64 + p] * beta[b * Cz + c0 + cl];
            Bs[cl][p] = W_s[(c0 + cl) * Kz + ktile * 64 + p];
        }
        __syncthreads();
        #pragma unroll 4
        for (int cc = 0; cc < 64; cc++) {
            const float4 av = *(const float4*)&As[cc][pq << 2];
            const float4 bv = *(const float4*)&Bs[cc][kq << 2];
            acc[0][0] = fmaf(av.x, bv.x, acc[0][0]);
            acc[0][1] = fmaf(av.x, bv.y, acc[0][1]);
            acc[0][2] = fmaf(av.x, bv.z, acc[0][2]);
            acc[0][3] = fmaf(av.x, bv.w, acc[0][3]);
            acc[1][0] = fmaf(av.y, bv.x, acc[1][0]);
            acc[1][1] = fmaf(av.y, bv.y, acc[1][1]);
            acc[1][2] = fmaf(av.y, bv.z, acc[1][2]);
            acc[1][3] = fmaf(av.y, bv.w, acc[1][3]);
            acc[2][0] = fmaf(av.z, bv.x, acc[2][0]);
            acc[2][1] = fmaf(av.z, bv.y, acc[2][1]);
            acc[2][2] = fmaf(av.z, bv.z, acc[2][2]);
            acc[2][3] = fmaf(av.z, bv.w, acc[2][3]);
            acc[3][0] = fmaf(av.w, bv.x, acc[3][0]);
            acc[3][1] = fmaf(av.w, bv.y, acc[3][1]);
            acc[3][2] = fmaf(av.w, bv.z, acc[3][2]);
            acc[3][3] = fmaf(av.w, bv.w, acc[3][3]);
        }
        __syncthreads();
    }
    float* dst = part + (size_t)((cslice * Bz + b) * Pz) * Kz + ktile * 64 + (kq << 2);
    #pragma unroll
    for (int i = 0; i < 4; i++) {
        int p = (pq << 2) + i;
        float4 w = make_float4(acc[i][0], acc[i][1], acc[i][2], acc[i][3]);
        *(float4*)&dst[(size_t)p * Kz] = w;
    }
}

// ---- spatial scores + batch softmax fused: block per p, wave per b → alpha[b][p] ----
__global__ __launch_bounds__(512) void k_atts_score(const float* __restrict__ spart,
                                                    const float* __restrict__ qpart,
                                                    const float* __restrict__ b_s,
                                                    const float* __restrict__ W_i,
                                                    float* __restrict__ alpha) {
    int p = blockIdx.x;
    int b = threadIdx.x >> 6, lane = threadIdx.x & 63;
    const float4* bs4 = (const float4*)b_s;
    const float4* wi4 = (const float4*)W_i;
    const float4* qp4 = (const float4*)qpart;
    const float4* sp4 = (const float4*)spart;
    float acc = 0.0f;
    #pragma unroll
    for (int i = 0; i < 2; i++) {
        int kq = i * 64 + lane;
        float4 q = bs4[kq];
        #pragma unroll
        for (int ch = 0; ch < 4; ch++) {
            float4 t = qp4[((ch * 2 + 1) * Bz + b) * (Kz / 4) + kq];
            q.x += t.x; q.y += t.y; q.z += t.z; q.w += t.w;
        }
        float4 s = make_float4(0.f, 0.f, 0.f, 0.f);
        #pragma unroll
        for (int cs = 0; cs < 4; cs++) {
            float4 t = sp4[(size_t)((cs * Bz + b) * Pz + p) * (Kz / 4) + kq];
            s.x += t.x; s.y += t.y; s.z += t.z; s.w += t.w;
        }
        float4 wi = wi4[kq];
        acc += tanhf(s.x + q.x) * wi.x;
        acc += tanhf(s.y + q.y) * wi.y;
        acc += tanhf(s.z + q.z) * wi.z;
        acc += tanhf(s.w + q.w) * wi.w;
    }
    acc = waveReduce(acc);
    __shared__ float sL[Bz];
    if (lane == 0) sL[b] = acc;
    __syncthreads();
    if (threadIdx.x < Bz) {
        float m = -1e30f;
        #pragma unroll
        for (int j = 0; j < Bz; j++) m = fmaxf(m, sL[j]);
        float s = 0.0f;
        #pragma unroll
        for (int j = 0; j < Bz; j++) s += expf(sL[j] - m);
        alpha[threadIdx.x * Pz + p] = expf(sL[threadIdx.x] - m) / s;
    }
}

// ---- awe → xcat[b][512+c]; also builds xcat emb/h segments ----
__global__ void k_awe_xcat(const float* __restrict__ enc, const float* __restrict__ beta,
                           const float* __restrict__ alpha, const float* __restrict__ emb,
                           const int* __restrict__ caps, const float* __restrict__ h,
                           float* __restrict__ xcat, int t) {
    int bid = blockIdx.x;
    int tid = threadIdx.x;
    if (bid < 4096) {
        int w = bid * 4 + (tid >> 6);       // (b*Cz + c)
        int lane = tid & 63;
        int b = w >> 11;
        int c = w & 2047;
        float a = alpha[b * Pz + lane];
        float e = enc[w * 64 + lane];
        float v = waveReduce(e * a);
        if (lane == 0) xcat[b * 3072 + Ez + c] = beta[w] * v * (1.0f / 64.0f);
    } else {
        int idx = (bid - 4096) * 256 + tid;  // 0..8191
        int b = idx >> 10, r = idx & 1023;
        if (r < Ez) {
            xcat[b * 3072 + r] = emb[(size_t)caps[b * T1z + t] * Ez + r];
        } else {
            xcat[b * 3072 + 2560 + (r - Ez)] = h[b * Dz + (r - Ez)];
        }
    }
}

// ---- gates partials: wave per (chunk, j-pair); lanes = (b, e8); float4 ----
__global__ __launch_bounds__(256) void k_gates(const float* __restrict__ xcat,
                                               const float* __restrict__ W_ih,
                                               const float* __restrict__ W_hh,
                                               float* __restrict__ gpart) {
    int wid = blockIdx.x * 4 + (threadIdx.x >> 6);  // 0..2047
    int lane = threadIdx.x & 63;
    int chunk = wid >> 10;                          // K-half: e in [chunk*1536, +1536)
    int jp = wid & 1023;
    int j0 = jp * 2;
    int b = lane >> 3, e8 = lane & 7;
    const float* xb = xcat + b * 3072 + chunk * 1536;
    float acc0 = 0.0f, acc1 = 0.0f;
    #pragma unroll 6
    for (int i = 0; i < 48; i++) {
        int e = (i * 8 + e8) * 4;            // within chunk
        float4 xv = *(const float4*)(xb + e);
        int eg = chunk * 1536 + e;
        const float *w0p, *w1p;
        if (chunk * 1536 + i * 32 < 2560) {  // wave-uniform branch
            w0p = W_ih + (size_t)j0 * 2560 + eg;
            w1p = W_ih + (size_t)(j0 + 1) * 2560 + eg;
        } else {
            w0p = W_hh + (size_t)j0 * Dz + (eg - 2560);
            w1p = W_hh + (size_t)(j0 + 1) * Dz + (eg - 2560);
        }
        float4 w0 = *(const float4*)w0p;
        float4 w1 = *(const float4*)w1p;
        acc0 = fmaf(xv.x, w0.x, acc0); acc0 = fmaf(xv.y, w0.y, acc0);
        acc0 = fmaf(xv.z, w0.z, acc0); acc0 = fmaf(xv.w, w0.w, acc0);
        acc1 = fmaf(xv.x, w1.x, acc1); acc1 = fmaf(xv.y, w1.y, acc1);
        acc1 = fmaf(xv.z, w1.z, acc1); acc1 = fmaf(xv.w, w1.w, acc1);
    }
    #pragma unroll
    for (int m = 1; m < 8; m <<= 1) {
        acc0 += __shfl_xor(acc0, m);
        acc1 += __shfl_xor(acc1, m);
    }
    if (e8 == 0) gpart[(chunk * Bz + b) * 2048 + j0] = acc0;
    else if (e8 == 1) gpart[(chunk * Bz + b) * 2048 + j0 + 1] = acc1;
}

// ---- LSTM cell: sum gate partials + biases, update h,c ----
__global__ void k_cell(const float* __restrict__ gpart,
                       const float* __restrict__ b_ih, const float* __restrict__ b_hh,
                       float* __restrict__ h, float* __restrict__ c) {
    int idx = blockIdx.x * 256 + threadIdx.x;    // [0, B*D)
    int b = idx >> 9, d = idx & 511;
    const float* g0 = gpart + b * 2048;
    const float* g1 = gpart + (Bz + b) * 2048;
    float gi = g0[d] + g1[d] + b_ih[d] + b_hh[d];
    float gf = g0[512 + d] + g1[512 + d] + b_ih[512 + d] + b_hh[512 + d];
    float gg = g0[1024 + d] + g1[1024 + d] + b_ih[1024 + d] + b_hh[1024 + d];
    float go = g0[1536 + d] + g1[1536 + d] + b_ih[1536 + d] + b_hh[1536 + d];
    float ig = sigf(gi), fg = sigf(gf), gt = tanhf(gg), og = sigf(go);
    float cn = fg * c[idx] + ig * gt;
    c[idx] = cn;
    h[idx] = og * tanhf(cn);
}

// ---- preds: wave per v; lanes = (b, d8); float4 ----
__global__ __launch_bounds__(256) void k_preds(const float* __restrict__ h,
                                               const float* __restrict__ W_fc,
                                               const float* __restrict__ b_fc,
                                               float* __restrict__ out, int t) {
    int v = blockIdx.x * 4 + (threadIdx.x >> 6);
    int lane = threadIdx.x & 63;
    int b = lane >> 3, d8 = lane & 7;
    const float4* Wv = (const float4*)(W_fc + (size_t)v * Dz);
    const float4* hv = (const float4*)(h + b * Dz);
    float acc = 0.0f;
    #pragma unroll
    for (int i = 0; i < 16; i++) {
        float4 w = Wv[i * 8 + d8];
        float4 x = hv[i * 8 + d8];
        acc = fmaf(x.x, w.x, acc); acc = fmaf(x.y, w.y, acc);
        acc = fmaf(x.z, w.z, acc); acc = fmaf(x.w, w.w, acc);
    }
    #pragma unroll
    for (int m = 1; m < 8; m <<= 1) acc += __shfl_xor(acc, m);
    if (d8 == 0) out[((size_t)b * Tz + t) * Vz + v] = acc + b_fc[v];
}

extern "C" void kernel_launch(void* const* d_in, const int* in_sizes, int n_in,
                              void* d_out, int out_size, void* d_ws, size_t ws_size,
                              hipStream_t stream) {
    const float* enc      = (const float*)d_in[0];
    const int*   caps     = (const int*)d_in[1];
    const int*   caplen   = (const int*)d_in[2];
    const float* W_c      = (const float*)d_in[3];
    const float* W_hc     = (const float*)d_in[4];
    const float* W_i_hat  = (const float*)d_in[5];
    const float* b_c      = (const float*)d_in[6];
    const float* W_s      = (const float*)d_in[8];
    const float* W_hs     = (const float*)d_in[9];
    const float* W_i      = (const float*)d_in[10];
    const float* b_s      = (const float*)d_in[11];
    const float* emb      = (const float*)d_in[13];
    const float* W_ih     = (const float*)d_in[14];
    const float* W_hh     = (const float*)d_in[15];
    const float* b_ih     = (const float*)d_in[16];
    const float* b_hh     = (const float*)d_in[17];
    const float* W_init_h = (const float*)d_in[18];
    const float* b_init_h = (const float*)d_in[19];
    const float* W_init_c = (const float*)d_in[20];
    const float* b_init_c = (const float*)d_in[21];
    const float* W_fc     = (const float*)d_in[22];
    const float* b_fc     = (const float*)d_in[23];
    float* out = (float*)d_out;
    float* ws  = (float*)d_ws;

    float* vmean = ws;                  // 16384
    float* h     = vmean + 16384;       // 4096
    float* c     = h + 4096;            // 4096
    float* qpart = c + 4096;            // 4*2*8*512 = 32768
    float* beta  = qpart + 32768;       // 16384
    float* alpha = beta + 16384;        // 512
    float* xcat  = alpha + 512;         // 8*3072 = 24576
    float* gpart = xcat + 24576;        // 2*8*2048 = 32768
    float* spart = gpart + 32768;       // 4*8*64*512 = 1048576

    k_tail<<<25, 256, 0, stream>>>(caps, caplen, out);
    k_vmean<<<(Bz * Cz * 64) / 256, 256, 0, stream>>>(enc, vmean);
    k_init_hc<<<(2 * Bz * Dz * 64) / 256, 256, 0, stream>>>(vmean, W_init_h, b_init_h,
                                                            W_init_c, b_init_c, h, c);
    for (int t = 0; t < Tz; t++) {
        k_qcqs<<<128, 256, 0, stream>>>(h, W_hc, W_hs, qpart);
        k_attc_beta<<<Cz, 512, 0, stream>>>(vmean, W_c, b_c, qpart, W_i_hat, beta);
        k_atts_gemm<<<256, 256, 0, stream>>>(enc, beta, W_s, spart);
        k_atts_score<<<Pz, 512, 0, stream>>>(spart, qpart, b_s, W_i, alpha);
        k_awe_xcat<<<4096 + 32, 256, 0, stream>>>(enc, beta, alpha, emb, caps, h, xcat, t);
        k_gates<<<512, 256, 0, stream>>>(xcat, W_ih, W_hh, gpart);
        k_cell<<<(Bz * Dz) / 256, 256, 0, stream>>>(gpart, b_ih, b_hh, h, c);
        k_preds<<<Vz / 4, 256, 0, stream>>>(h, W_fc, b_fc, out, t);
    }
}